// Round 9
// baseline (124.646 us; speedup 1.0000x reference)
//
#include <hip/hip_runtime.h>
#include <cmath>

#define D_MODEL 1792
#define BB      256
#define II      2048          // inner dim
#define FOURI   8192
#define G       2048          // whole resident rounds (8 blocks/CU x 256 CU)

__device__ __forceinline__ float sigm(float v) { return 1.0f / (1.0f + expf(-v)); }

__device__ __forceinline__ float waveReduce(float s) {
    #pragma unroll
    for (int off = 32; off > 0; off >>= 1) s += __shfl_down(s, off, 64);
    return s;
}

__device__ __forceinline__ float dot4(float4 a, float4 b) {
    return a.x * b.x + a.y * b.y + a.z * b.z + a.w * b.w;
}

// ---------------------------------------------------------------------------
// K0: block b: step-0 cell row b (waves 0,2,3 = gates i,g,o; f skipped, c0=0)
//     INTERLEAVED with ih1 row 4b+wave. One fused load loop -> 2x MLP.
// ---------------------------------------------------------------------------
__global__ __launch_bounds__(256) void k_first(
    const float* __restrict__ x, const float* __restrict__ y,
    const float* __restrict__ Wih5,
    const float* __restrict__ bih5, const float* __restrict__ bhh5,
    float* __restrict__ h0, float* __restrict__ c0, float* __restrict__ gih1)
{
    __shared__ float partial[4];
    const int tid = threadIdx.x, wave = tid >> 6, lane = tid & 63;
    const int b = blockIdx.x;
    const int rowI = b * 4 + wave;

    const float* wc = Wih5 + ((size_t)wave * II + b) * (size_t)II;      // cell gate row
    const float* wi = Wih5 + ((size_t)FOURI + rowI) * (size_t)II;       // ih1 row
    const float* x1 = x + D_MODEL;
    const float* y1 = y + BB;

    float sc = 0.f, si = 0.f;
    #pragma unroll
    for (int p = 0; p < 8; ++p) {
        const int j = p * 256 + lane * 4;
        float4 e  = *(const float4*)(wi + j);
        float4 v1 = (p < 7) ? *(const float4*)(x1 + j)
                            : *(const float4*)(y1 + (j - D_MODEL));
        si += dot4(e, v1);
        if (wave != 1) {                                  // f-gate skipped
            float4 a  = *(const float4*)(wc + j);
            float4 v0 = (p < 7) ? *(const float4*)(x + j)
                                : *(const float4*)(y + (j - D_MODEL));
            sc += dot4(a, v0);
        }
    }
    si = waveReduce(si);
    if (lane == 0)
        gih1[rowI] = si + bih5[FOURI + rowI] + bhh5[FOURI + rowI];
    if (wave != 1) {
        sc = waveReduce(sc);
        if (lane == 0)
            partial[wave] = sc + bih5[wave * II + b] + bhh5[wave * II + b];
    }
    __syncthreads();
    if (tid == 0) {
        const float cc = sigm(partial[0]) * tanhf(partial[2]);
        c0[b] = cc;
        h0[b] = sigm(partial[3]) * tanhf(cc);
    }
}

// ---------------------------------------------------------------------------
// K1..K3: block b: cell row b for step t INTERLEAVED with ih row 4b+wave for
//         step t+1. Single fused load loop, reduces after, one sync.
// ---------------------------------------------------------------------------
__global__ __launch_bounds__(256) void k_mid(
    const float* __restrict__ Whh,    // (8192,2048) step t
    const float* __restrict__ gih_t,  // (8192)
    const float* __restrict__ h_in, float* __restrict__ h_out,
    float* __restrict__ c,
    const float* __restrict__ WihN,   // (8192,2048) step t+1
    const float* __restrict__ bihN, const float* __restrict__ bhhN,
    const float* __restrict__ xN, const float* __restrict__ yN,
    float* __restrict__ gihN)
{
    __shared__ float partial[4];
    const int tid = threadIdx.x, wave = tid >> 6, lane = tid & 63;
    const int b = blockIdx.x;
    const int rowI = b * 4 + wave;

    const float* wc = Whh  + ((size_t)wave * II + b) * (size_t)II;
    const float* wi = WihN + (size_t)rowI * (size_t)II;

    float sc = 0.f, si = 0.f;
    #pragma unroll
    for (int p = 0; p < 8; ++p) {
        const int j = p * 256 + lane * 4;
        float4 a  = *(const float4*)(wc + j);
        float4 hv = *(const float4*)(h_in + j);
        sc += dot4(a, hv);
        float4 e  = *(const float4*)(wi + j);
        float4 v  = (p < 7) ? *(const float4*)(xN + j)
                            : *(const float4*)(yN + (j - D_MODEL));
        si += dot4(e, v);
    }
    si = waveReduce(si);
    if (lane == 0) gihN[rowI] = si + bihN[rowI] + bhhN[rowI];
    sc = waveReduce(sc);
    if (lane == 0) partial[wave] = sc + gih_t[wave * II + b];
    __syncthreads();
    if (tid == 0) {
        const float cc = sigm(partial[1]) * c[b]
                       + sigm(partial[0]) * tanhf(partial[2]);
        c[b] = cc;
        h_out[b] = sigm(partial[3]) * tanhf(cc);
    }
}

// ---------------------------------------------------------------------------
// K4: block b: cell row b (step 4); blocks 0..255 additionally interleave the
//     final-cell ih row (compact j = 4b+wave over x5, 7 KB).
// ---------------------------------------------------------------------------
__global__ __launch_bounds__(256) void k4(
    const float* __restrict__ Whh4, const float* __restrict__ gih4,
    const float* __restrict__ h_in, float* __restrict__ h_out,
    float* __restrict__ c,
    const float* __restrict__ WihF, const float* __restrict__ bihF,
    const float* __restrict__ bhhF, const float* __restrict__ x5,
    float* __restrict__ gihF)
{
    __shared__ float partial[4];
    const int tid = threadIdx.x, wave = tid >> 6, lane = tid & 63;
    const int b = blockIdx.x;

    const float* wc = Whh4 + ((size_t)wave * II + b) * (size_t)II;
    const int jF = b * 4 + wave;                       // [0,1024) when b<256
    const int rowF = (jF >> 8) * II + D_MODEL + (jF & 255);
    const float* wf = WihF + (size_t)rowF * (size_t)D_MODEL;
    const bool doF = (b < BB);

    float sc = 0.f, sf = 0.f;
    #pragma unroll
    for (int p = 0; p < 8; ++p) {
        const int j = p * 256 + lane * 4;
        float4 a  = *(const float4*)(wc + j);
        float4 hv = *(const float4*)(h_in + j);
        sc += dot4(a, hv);
        if (doF && p < 7) {
            float4 e = *(const float4*)(wf + j);
            float4 v = *(const float4*)(x5 + j);
            sf += dot4(e, v);
        }
    }
    if (doF) {
        sf = waveReduce(sf);
        if (lane == 0) gihF[jF] = sf + bihF[rowF] + bhhF[rowF];
    }
    sc = waveReduce(sc);
    if (lane == 0) partial[wave] = sc + gih4[wave * II + b];
    __syncthreads();
    if (tid == 0) {
        const float cc = sigm(partial[1]) * c[b]
                       + sigm(partial[0]) * tanhf(partial[2]);
        c[b] = cc;
        h_out[b] = sigm(partial[3]) * tanhf(cc);
    }
}

// ---------------------------------------------------------------------------
// K5: final cell, 256 blocks: row 1792+b -> out[b].
// ---------------------------------------------------------------------------
__global__ __launch_bounds__(256) void k5(
    const float* __restrict__ WhhF, const float* __restrict__ gihF,
    const float* __restrict__ h_in, const float* __restrict__ c,
    float* __restrict__ out)
{
    __shared__ float partial[4];
    const int tid = threadIdx.x, wave = tid >> 6, lane = tid & 63;
    const int b = blockIdx.x;                     // 0..255
    const int r = D_MODEL + b;

    const float* wr = WhhF + ((size_t)wave * II + r) * (size_t)II;
    float s = 0.f;
    #pragma unroll
    for (int p = 0; p < 8; ++p) {
        const int j = p * 256 + lane * 4;
        s += dot4(*(const float4*)(wr + j), *(const float4*)(h_in + j));
    }
    s = waveReduce(s);
    if (lane == 0) partial[wave] = s + gihF[wave * BB + b];
    __syncthreads();
    if (tid == 0) {
        const float cc = sigm(partial[1]) * c[r]
                       + sigm(partial[0]) * tanhf(partial[2]);
        out[b] = sigm(partial[3]) * tanhf(cc);
    }
}

extern "C" void kernel_launch(void* const* d_in, const int* in_sizes, int n_in,
                              void* d_out, int out_size, void* d_ws, size_t ws_size,
                              hipStream_t stream) {
    const float* x    = (const float*)d_in[0];
    const float* y    = (const float*)d_in[1];
    const float* Wih5 = (const float*)d_in[2];
    const float* Whh5 = (const float*)d_in[3];
    const float* bih5 = (const float*)d_in[4];
    const float* bhh5 = (const float*)d_in[5];
    const float* WihF = (const float*)d_in[6];
    const float* WhhF = (const float*)d_in[7];
    const float* bihF = (const float*)d_in[8];
    const float* bhhF = (const float*)d_in[9];
    float* out = (float*)d_out;

    float* ws   = (float*)d_ws;
    float* gihA = ws;                  // 8192
    float* gihB = gihA + FOURI;        // 8192
    float* gihF = gihB + FOURI;        // 1024
    float* hA   = gihF + 1024;         // 2048
    float* hB   = hA + II;             // 2048
    float* cbuf = hB + II;             // 2048

    const size_t WOFF = (size_t)FOURI * II;

    // K0: cell0 (f-gate skipped) + ih1 -> gihA ; h0 -> hA
    k_first<<<G, 256, 0, stream>>>(x, y, Wih5, bih5, bhh5, hA, cbuf, gihA);

    // K1: cell1 (gihA, hA->hB) + ih2 -> gihB
    k_mid<<<G, 256, 0, stream>>>(
        Whh5 + 1 * WOFF, gihA, hA, hB, cbuf,
        Wih5 + 2 * WOFF, bih5 + 2 * FOURI, bhh5 + 2 * FOURI,
        x + 2 * D_MODEL, y + 2 * BB, gihB);

    // K2: cell2 (gihB, hB->hA) + ih3 -> gihA
    k_mid<<<G, 256, 0, stream>>>(
        Whh5 + 2 * WOFF, gihB, hB, hA, cbuf,
        Wih5 + 3 * WOFF, bih5 + 3 * FOURI, bhh5 + 3 * FOURI,
        x + 3 * D_MODEL, y + 3 * BB, gihA);

    // K3: cell3 (gihA, hA->hB) + ih4 -> gihB
    k_mid<<<G, 256, 0, stream>>>(
        Whh5 + 3 * WOFF, gihA, hA, hB, cbuf,
        Wih5 + 4 * WOFF, bih5 + 4 * FOURI, bhh5 + 4 * FOURI,
        x + 4 * D_MODEL, y + 4 * BB, gihB);

    // K4: cell4 (gihB, hB->hA) + final-cell ih -> gihF
    k4<<<G, 256, 0, stream>>>(
        Whh5 + 4 * WOFF, gihB, hB, hA, cbuf,
        WihF, bihF, bhhF, x + 5 * D_MODEL, gihF);

    // K5: final cell -> out
    k5<<<BB, 256, 0, stream>>>(WhhF, gihF, hA, cbuf, out);
}

// Round 10
// 121.659 us; speedup vs baseline: 1.0246x; 1.0246x over previous
//
#include <hip/hip_runtime.h>
#include <cmath>

#define D_MODEL 1792
#define BB      256
#define II      2048          // inner dim
#define FOURI   8192
#define G       2048          // whole resident rounds (8 blocks/CU x 256 CU)

__device__ __forceinline__ float sigm(float v) { return 1.0f / (1.0f + expf(-v)); }

__device__ __forceinline__ float waveReduce(float s) {
    #pragma unroll
    for (int off = 32; off > 0; off >>= 1) s += __shfl_down(s, off, 64);
    return s;
}

__device__ __forceinline__ float dot4(float4 a, float4 b) {
    return a.x * b.x + a.y * b.y + a.z * b.z + a.w * b.w;
}

// dot of one 2048-wide weight row with concat(x_t[1792], y_t[256])
__device__ __forceinline__ float dotConcat(const float* __restrict__ w,
                                           const float* __restrict__ xt,
                                           const float* __restrict__ yt,
                                           int lane) {
    float s = 0.f;
    #pragma unroll
    for (int p = 0; p < 8; ++p) {
        const int j = p * 256 + lane * 4;
        float4 a = *(const float4*)(w + j);
        float4 b = (p < 7) ? *(const float4*)(xt + j)
                           : *(const float4*)(yt + (j - D_MODEL));
        s += dot4(a, b);
    }
    return s;
}

// ---------------------------------------------------------------------------
// K0 (unchanged from R8, 120.1us config): block b: step-0 cell row b
// (waves 0,2,3 = gates i,g,o; f skipped) then ih1 row 4b+wave.
// ---------------------------------------------------------------------------
__global__ __launch_bounds__(256) void k_first(
    const float* __restrict__ x, const float* __restrict__ y,
    const float* __restrict__ Wih5,
    const float* __restrict__ bih5, const float* __restrict__ bhh5,
    float* __restrict__ h0, float* __restrict__ c0, float* __restrict__ gih1)
{
    __shared__ float partial[4];
    const int tid = threadIdx.x, wave = tid >> 6, lane = tid & 63;
    const int b = blockIdx.x;

    if (wave != 1) {
        const float* wr = Wih5 + ((size_t)wave * II + b) * (size_t)II;
        float s = dotConcat(wr, x, y, lane);
        s = waveReduce(s);
        if (lane == 0)
            partial[wave] = s + bih5[wave * II + b] + bhh5[wave * II + b];
    }
    __syncthreads();
    if (tid == 0) {
        const float cc = sigm(partial[0]) * tanhf(partial[2]);
        c0[b] = cc;
        h0[b] = sigm(partial[3]) * tanhf(cc);
    }
    {
        const int row = b * 4 + wave;
        const float* wr = Wih5 + ((size_t)FOURI + row) * (size_t)II;
        float s = dotConcat(wr, x + D_MODEL, y + BB, lane);
        s = waveReduce(s);
        if (lane == 0)
            gih1[row] = s + bih5[FOURI + row] + bhh5[FOURI + row];
    }
}

// ---------------------------------------------------------------------------
// K1..K3 (NEW): linear 16KB stream per wave.
//   blocks 0..1023  : cell rows 2b, 2b+1. Wave w reads gate-w rows 2b..2b+1
//                     (contiguous 16KB) computing both dots vs h_in.
//   blocks 1024..2047: ih rows 8u..8u+7 for step t+1. Wave w reads rows
//                     8u+2w..8u+2w+1 (contiguous 16KB) vs concat(xN,yN).
// ---------------------------------------------------------------------------
__global__ __launch_bounds__(256) void k_mid(
    const float* __restrict__ Whh,    // (8192,2048) step t
    const float* __restrict__ gih_t,  // (8192)
    const float* __restrict__ h_in, float* __restrict__ h_out,
    float* __restrict__ c,
    const float* __restrict__ WihN,   // (8192,2048) step t+1
    const float* __restrict__ bihN, const float* __restrict__ bhhN,
    const float* __restrict__ xN, const float* __restrict__ yN,
    float* __restrict__ gihN)
{
    __shared__ float partial[4][2];
    const int tid = threadIdx.x, wave = tid >> 6, lane = tid & 63;
    const int b = blockIdx.x;

    if (b < 1024) {
        const int r0 = 2 * b;
        const float* base = Whh + ((size_t)wave * II + r0) * (size_t)II;
        float s0 = 0.f, s1 = 0.f;
        #pragma unroll
        for (int p = 0; p < 16; ++p) {
            const int j = p * 256 + lane * 4;        // linear 16KB walk
            float4 a = *(const float4*)(base + j);
            const int q = p & 7;
            float4 hv = *(const float4*)(h_in + q * 256 + lane * 4);
            if (p < 8) s0 += dot4(a, hv); else s1 += dot4(a, hv);
        }
        s0 = waveReduce(s0);
        s1 = waveReduce(s1);
        if (lane == 0) {
            partial[wave][0] = s0 + gih_t[wave * II + r0];
            partial[wave][1] = s1 + gih_t[wave * II + r0 + 1];
        }
        __syncthreads();
        if (tid < 2) {
            const int r = r0 + tid;
            const float cc = sigm(partial[1][tid]) * c[r]
                           + sigm(partial[0][tid]) * tanhf(partial[2][tid]);
            c[r] = cc;
            h_out[r] = sigm(partial[3][tid]) * tanhf(cc);
        }
    } else {
        const int u = b - 1024;
        const int row0 = 8 * u + 2 * wave;
        const float* base = WihN + (size_t)row0 * (size_t)II;
        float s0 = 0.f, s1 = 0.f;
        #pragma unroll
        for (int p = 0; p < 16; ++p) {
            const int j = p * 256 + lane * 4;        // linear 16KB walk
            float4 a = *(const float4*)(base + j);
            const int q = p & 7;
            const int jj = q * 256 + lane * 4;
            float4 v = (q < 7) ? *(const float4*)(xN + jj)
                               : *(const float4*)(yN + (jj - D_MODEL));
            if (p < 8) s0 += dot4(a, v); else s1 += dot4(a, v);
        }
        s0 = waveReduce(s0);
        s1 = waveReduce(s1);
        if (lane == 0) {
            gihN[row0]     = s0 + bihN[row0]     + bhhN[row0];
            gihN[row0 + 1] = s1 + bihN[row0 + 1] + bhhN[row0 + 1];
        }
    }
}

// ---------------------------------------------------------------------------
// K4 (unchanged from R8): cell row b (step 4); blocks 0..255 also do the
// final-cell ih quad (compact j = 4b+wave over x5).
// ---------------------------------------------------------------------------
__global__ __launch_bounds__(256) void k4(
    const float* __restrict__ Whh4, const float* __restrict__ gih4,
    const float* __restrict__ h_in, float* __restrict__ h_out,
    float* __restrict__ c,
    const float* __restrict__ WihF, const float* __restrict__ bihF,
    const float* __restrict__ bhhF, const float* __restrict__ x5,
    float* __restrict__ gihF)
{
    __shared__ float partial[4];
    const int tid = threadIdx.x, wave = tid >> 6, lane = tid & 63;
    const int b = blockIdx.x;

    {
        const float* wr = Whh4 + ((size_t)wave * II + b) * (size_t)II;
        float s = 0.f;
        #pragma unroll
        for (int p = 0; p < 8; ++p) {
            const int j = p * 256 + lane * 4;
            s += dot4(*(const float4*)(wr + j), *(const float4*)(h_in + j));
        }
        s = waveReduce(s);
        if (lane == 0) partial[wave] = s + gih4[wave * II + b];
    }
    __syncthreads();
    if (tid == 0) {
        const float cc = sigm(partial[1]) * c[b]
                       + sigm(partial[0]) * tanhf(partial[2]);
        c[b] = cc;
        h_out[b] = sigm(partial[3]) * tanhf(cc);
    }

    if (b < BB) {
        const int j = b * 4 + wave;                  // [0,1024)
        const int row = (j >> 8) * II + D_MODEL + (j & 255);
        const float* wr = WihF + (size_t)row * (size_t)D_MODEL;
        float s = 0.f;
        #pragma unroll
        for (int p = 0; p < 7; ++p) {
            const int jj = p * 256 + lane * 4;
            float4 a = *(const float4*)(wr + jj);
            float4 v = *(const float4*)(x5 + jj);
            s += dot4(a, v);
        }
        s = waveReduce(s);
        if (lane == 0) gihF[j] = s + bihF[row] + bhhF[row];
    }
}

// ---------------------------------------------------------------------------
// K5 (unchanged from R8): final cell, 256 blocks: row 1792+b -> out[b].
// ---------------------------------------------------------------------------
__global__ __launch_bounds__(256) void k5(
    const float* __restrict__ WhhF, const float* __restrict__ gihF,
    const float* __restrict__ h_in, const float* __restrict__ c,
    float* __restrict__ out)
{
    __shared__ float partial[4];
    const int tid = threadIdx.x, wave = tid >> 6, lane = tid & 63;
    const int b = blockIdx.x;                     // 0..255
    const int r = D_MODEL + b;

    const float* wr = WhhF + ((size_t)wave * II + r) * (size_t)II;
    float s = 0.f;
    #pragma unroll
    for (int p = 0; p < 8; ++p) {
        const int j = p * 256 + lane * 4;
        s += dot4(*(const float4*)(wr + j), *(const float4*)(h_in + j));
    }
    s = waveReduce(s);
    if (lane == 0) partial[wave] = s + gihF[wave * BB + b];
    __syncthreads();
    if (tid == 0) {
        const float cc = sigm(partial[1]) * c[r]
                       + sigm(partial[0]) * tanhf(partial[2]);
        out[b] = sigm(partial[3]) * tanhf(cc);
    }
}

extern "C" void kernel_launch(void* const* d_in, const int* in_sizes, int n_in,
                              void* d_out, int out_size, void* d_ws, size_t ws_size,
                              hipStream_t stream) {
    const float* x    = (const float*)d_in[0];
    const float* y    = (const float*)d_in[1];
    const float* Wih5 = (const float*)d_in[2];
    const float* Whh5 = (const float*)d_in[3];
    const float* bih5 = (const float*)d_in[4];
    const float* bhh5 = (const float*)d_in[5];
    const float* WihF = (const float*)d_in[6];
    const float* WhhF = (const float*)d_in[7];
    const float* bihF = (const float*)d_in[8];
    const float* bhhF = (const float*)d_in[9];
    float* out = (float*)d_out;

    float* ws   = (float*)d_ws;
    float* gihA = ws;                  // 8192
    float* gihB = gihA + FOURI;        // 8192
    float* gihF = gihB + FOURI;        // 1024
    float* hA   = gihF + 1024;         // 2048
    float* hB   = hA + II;             // 2048
    float* cbuf = hB + II;             // 2048

    const size_t WOFF = (size_t)FOURI * II;

    // K0: cell0 (f-gate skipped) + ih1 -> gihA ; h0 -> hA
    k_first<<<G, 256, 0, stream>>>(x, y, Wih5, bih5, bhh5, hA, cbuf, gihA);

    // K1: cell1 (gihA, hA->hB) + ih2 -> gihB
    k_mid<<<G, 256, 0, stream>>>(
        Whh5 + 1 * WOFF, gihA, hA, hB, cbuf,
        Wih5 + 2 * WOFF, bih5 + 2 * FOURI, bhh5 + 2 * FOURI,
        x + 2 * D_MODEL, y + 2 * BB, gihB);

    // K2: cell2 (gihB, hB->hA) + ih3 -> gihA
    k_mid<<<G, 256, 0, stream>>>(
        Whh5 + 2 * WOFF, gihB, hB, hA, cbuf,
        Wih5 + 3 * WOFF, bih5 + 3 * FOURI, bhh5 + 3 * FOURI,
        x + 3 * D_MODEL, y + 3 * BB, gihA);

    // K3: cell3 (gihA, hA->hB) + ih4 -> gihB
    k_mid<<<G, 256, 0, stream>>>(
        Whh5 + 3 * WOFF, gihA, hA, hB, cbuf,
        Wih5 + 4 * WOFF, bih5 + 4 * FOURI, bhh5 + 4 * FOURI,
        x + 4 * D_MODEL, y + 4 * BB, gihB);

    // K4: cell4 (gihB, hB->hA) + final-cell ih -> gihF
    k4<<<G, 256, 0, stream>>>(
        Whh5 + 4 * WOFF, gihB, hB, hA, cbuf,
        WihF, bihF, bhhF, x + 5 * D_MODEL, gihF);

    // K5: final cell -> out
    k5<<<BB, 256, 0, stream>>>(WhhF, gihF, hA, cbuf, out);
}